// Round 6
// baseline (984.220 us; speedup 1.0000x reference)
//
#include <hip/hip_runtime.h>
#include <hip/hip_bf16.h>
#include <math.h>

// ---------------------------------------------------------------------------
// Round 5: fix partial-line-write RMW over-fetch (R5 FFN1 FETCH=103MB vs 13MB
// ideal): all gemm_bt epilogues stage C through a 64x136 LDS tile and emit
// coalesced uint4 stores (v^T via in-LDS gather; 8-aligned m-chunks never
// cross the 360-row batch boundary). head_k vectorized (was 79us latency-
// bound scalar loads). Weight transpose tiled through LDS.
// ws layout unchanged (191,365,120 B).
// ---------------------------------------------------------------------------

using bf16 = __hip_bfloat16;
typedef __attribute__((ext_vector_type(8))) short frag8;
typedef __attribute__((ext_vector_type(4))) float f32x4;

static __device__ __forceinline__ float wave_sum64(float v){
  #pragma unroll
  for (int o = 32; o >= 1; o >>= 1) v += __shfl_xor(v, o, 64);
  return v;
}

static __device__ __forceinline__ void gl_lds16(const bf16* g, bf16* l){
  __builtin_amdgcn_global_load_lds((const __attribute__((address_space(1))) void*)g,
                                   (__attribute__((address_space(3))) void*)l, 16, 0, 0);
}

static __device__ __forceinline__ unsigned pack2(float a, float b){
  union { bf16 h[2]; unsigned u; } u;
  u.h[0] = __float2bfloat16(a); u.h[1] = __float2bfloat16(b);
  return u.u;
}

// tiled fp32->bf16 transpose: dst[n*K+k] = src[k*N+n]. grid (K/32, N/32), 256 thr.
__global__ __launch_bounds__(256) void cvt_transpose(bf16* __restrict__ dst,
                                                     const float* __restrict__ src,
                                                     int K, int N){
  __shared__ float t[32][33];
  int kb = blockIdx.x * 32, nb = blockIdx.y * 32;
  int tx = threadIdx.x & 31, ty = threadIdx.x >> 5;   // ty 0..7
  #pragma unroll
  for (int dy = 0; dy < 32; dy += 8)
    t[ty + dy][tx] = src[(size_t)(kb + ty + dy) * N + nb + tx];
  __syncthreads();
  #pragma unroll
  for (int dy = 0; dy < 32; dy += 8)
    dst[(size_t)(nb + ty + dy) * K + kb + tx] = __float2bfloat16(t[tx][ty + dy]);
}

// embed + PE + scale -> x (bf16), LN1 -> xn (bf16). one wave/row, grid 23040.
__global__ __launch_bounds__(256) void embed_ln1(
    const int* __restrict__ src, const float* __restrict__ emb,
    const float* __restrict__ na, const float* __restrict__ nb,
    bf16* __restrict__ x, bf16* __restrict__ xn)
{
  int row  = blockIdx.x * 4 + (threadIdx.x >> 6);
  int lane = threadIdx.x & 63;
  int s = row % 360;
  int tok = src[row];
  float4 v = *(const float4*)(emb + (size_t)tok * 256 + lane * 4);
  float vv[4] = {v.x, v.y, v.z, v.w};
  if (s < 340){
    const float C = (-2.0f / 256.0f) * 13.287712379549449f;  // -2/D * log2(10000)
    #pragma unroll
    for (int t = 0; t < 4; t++){
      int c = lane * 4 + t;
      float ang = (float)s * exp2f(C * (float)c);
      float pe = (c & 1) ? cosf(ang) : sinf(ang);
      vv[t] = 16.0f * vv[t] + pe;
    }
  }
  float sum = wave_sum64(vv[0] + vv[1] + vv[2] + vv[3]);
  float mu = sum * (1.0f / 256.0f);
  float d0 = vv[0]-mu, d1 = vv[1]-mu, d2 = vv[2]-mu, d3 = vv[3]-mu;
  float sq = wave_sum64(d0*d0 + d1*d1 + d2*d2 + d3*d3);
  float inv = 1.0f / (sqrtf(sq * (1.0f / 255.0f)) + 1e-6f);
  bf16 xo[4] = { __float2bfloat16(vv[0]), __float2bfloat16(vv[1]),
                 __float2bfloat16(vv[2]), __float2bfloat16(vv[3]) };
  *(uint2*)(x + (size_t)row * 256 + lane * 4) = *(uint2*)xo;
  float4 a4 = *(const float4*)(na + lane * 4);
  float4 b4 = *(const float4*)(nb + lane * 4);
  bf16 o4[4] = { __float2bfloat16(a4.x * d0 * inv + b4.x),
                 __float2bfloat16(a4.y * d1 * inv + b4.y),
                 __float2bfloat16(a4.z * d2 * inv + b4.z),
                 __float2bfloat16(a4.w * d3 * inv + b4.w) };
  *(uint2*)(xn + (size_t)row * 256 + lane * 4) = *(uint2*)o4;
}

// LN over bf16 x -> bf16 xn. one wave per row. grid 23040.
__global__ __launch_bounds__(256) void ln_k(
    const bf16* __restrict__ x, const float* __restrict__ na,
    const float* __restrict__ nb, bf16* __restrict__ xn)
{
  int row  = blockIdx.x * 4 + (threadIdx.x >> 6);
  int lane = threadIdx.x & 63;
  uint2 raw = *(const uint2*)(x + (size_t)row * 256 + lane * 4);
  bf16* xr = (bf16*)&raw;
  float v0 = __bfloat162float(xr[0]), v1 = __bfloat162float(xr[1]);
  float v2 = __bfloat162float(xr[2]), v3 = __bfloat162float(xr[3]);
  float sum = wave_sum64(v0 + v1 + v2 + v3);
  float mu = sum * (1.0f / 256.0f);
  float d0 = v0-mu, d1 = v1-mu, d2 = v2-mu, d3 = v3-mu;
  float sq = wave_sum64(d0*d0 + d1*d1 + d2*d2 + d3*d3);
  float inv = 1.0f / (sqrtf(sq * (1.0f / 255.0f)) + 1e-6f);
  float4 a4 = *(const float4*)(na + lane * 4);
  float4 b4 = *(const float4*)(nb + lane * 4);
  bf16 o4[4] = { __float2bfloat16(a4.x * d0 * inv + b4.x),
                 __float2bfloat16(a4.y * d1 * inv + b4.y),
                 __float2bfloat16(a4.z * d2 * inv + b4.z),
                 __float2bfloat16(a4.w * d3 * inv + b4.w) };
  *(uint2*)(xn + (size_t)row * 256 + lane * 4) = *(uint2*)o4;
}

// C = A[M][K] @ Bt[N][K]^T + bias. 128x128 tile, BK=32, global_load_lds staging,
// LDS-staged coalesced epilogue.
// MODE 2: relu, bf16 row-major [M][N]
// MODE 3: bf16 residual in-place: xres[m*256+n] += acc (+bias)
// MODE 4: merged QKV (N=768): region = n0>>8: 0 q-layout, 1 k-layout, 2 v^T
template<int MODE>
__global__ __launch_bounds__(256) void gemm_bt(
    const bf16* __restrict__ A, int lda,
    const bf16* __restrict__ Bt, int ldb,
    const float* __restrict__ bias,
    bf16* __restrict__ outb, bf16* __restrict__ xres,
    int N, int K,
    const float* __restrict__ bq, const float* __restrict__ bk,
    const float* __restrict__ bv)
{
  __shared__ bf16 As[128 * 32];
  __shared__ bf16 Bs[128 * 32];
  __shared__ bf16 Cs[64][136];     // epilogue staging (272B row stride, 16B-aligned)
  int m0 = blockIdx.x * 128, n0 = blockIdx.y * 128;
  int tid = threadIdx.x;
  int wave = tid >> 6, lane = tid & 63;
  int wm = (wave >> 1) * 64, wn = (wave & 1) * 64;
  int r = lane & 15, qd = lane >> 4;

  int slot0 = wave * 128 + lane;
  int row0 = slot0 >> 2, c0 = slot0 & 3;
  int row1 = (slot0 + 64) >> 2, c1 = (slot0 + 64) & 3;
  const bf16* ag0 = A  + (size_t)(m0 + row0) * lda + c0 * 8;
  const bf16* ag1 = A  + (size_t)(m0 + row1) * lda + c1 * 8;
  const bf16* bg0 = Bt + (size_t)(n0 + row0) * ldb + c0 * 8;
  const bf16* bg1 = Bt + (size_t)(n0 + row1) * ldb + c1 * 8;
  bf16* lA0 = As + (size_t)(wave * 128) * 8;
  bf16* lA1 = As + (size_t)(wave * 128 + 64) * 8;
  bf16* lB0 = Bs + (size_t)(wave * 128) * 8;
  bf16* lB1 = Bs + (size_t)(wave * 128 + 64) * 8;

  f32x4 acc[4][4];
  #pragma unroll
  for (int mt = 0; mt < 4; mt++)
    #pragma unroll
    for (int nt = 0; nt < 4; nt++) acc[mt][nt] = (f32x4){0.f, 0.f, 0.f, 0.f};

  for (int k0 = 0; k0 < K; k0 += 32){
    gl_lds16(ag0, lA0); gl_lds16(ag1, lA1);
    gl_lds16(bg0, lB0); gl_lds16(bg1, lB1);
    ag0 += 32; ag1 += 32; bg0 += 32; bg1 += 32;
    __syncthreads();
    frag8 af[4], bfr[4];
    #pragma unroll
    for (int t = 0; t < 4; t++){
      af[t]  = *(const frag8*)(As + (wm + t * 16 + r) * 32 + qd * 8);
      bfr[t] = *(const frag8*)(Bs + (wn + t * 16 + r) * 32 + qd * 8);
    }
    #pragma unroll
    for (int mt = 0; mt < 4; mt++)
      #pragma unroll
      for (int nt = 0; nt < 4; nt++)
        acc[mt][nt] = __builtin_amdgcn_mfma_f32_16x16x32_bf16(af[mt], bfr[nt], acc[mt][nt], 0, 0, 0);
    __syncthreads();
  }

  // ---- LDS-staged epilogue: two 64-row halves ----
  const int region = (MODE == 4) ? (n0 >> 8) : 0;
  const float* bb = (MODE == 4) ? (region == 0 ? bq : region == 1 ? bk : bv) : bias;

  #pragma unroll
  for (int half = 0; half < 2; half++){
    if ((wave >> 1) == half){
      #pragma unroll
      for (int mt = 0; mt < 4; mt++)
        #pragma unroll
        for (int nt = 0; nt < 4; nt++)
          #pragma unroll
          for (int i = 0; i < 4; i++){
            int lm = mt * 16 + qd * 4 + i;
            int ln = wn + nt * 16 + r;
            float v = acc[mt][nt][i];
            if (MODE == 2){ v += bb[n0 + ln]; v = fmaxf(v, 0.0f); }
            else if (MODE == 3){ if (bb) v += bb[n0 + ln]; }
            else { v += bb[(n0 & 255) + ln]; }
            Cs[lm][ln] = __float2bfloat16(v);
          }
    }
    __syncthreads();
    int mbase = m0 + half * 64;
    if (MODE == 2){
      int lr = tid >> 2, seg = tid & 3;
      bf16* op = outb + (size_t)(mbase + lr) * N + n0 + seg * 32;
      #pragma unroll
      for (int j = 0; j < 4; j++)
        *(uint4*)(op + j * 8) = *(uint4*)(&Cs[lr][seg * 32 + j * 8]);
    } else if (MODE == 3){
      int lr = tid >> 2, seg = tid & 3;
      bf16* op = xres + (size_t)(mbase + lr) * 256 + n0 + seg * 32;
      #pragma unroll
      for (int j = 0; j < 4; j++){
        uint4 cv = *(uint4*)(&Cs[lr][seg * 32 + j * 8]);
        uint4 xv = *(uint4*)(op + j * 8);
        bf16* ca = (bf16*)&cv; bf16* xa = (bf16*)&xv;
        bf16 o8[8];
        #pragma unroll
        for (int t = 0; t < 8; t++)
          o8[t] = __float2bfloat16(__bfloat162float(ca[t]) + __bfloat162float(xa[t]));
        *(uint4*)(op + j * 8) = *(uint4*)o8;
      }
    } else {  // MODE 4
      if (region < 2){
        int lr = tid >> 2, seg = tid & 3;
        int m = mbase + lr;
        int b_ = m / 360, s = m - b_ * 360;
        int nnl = (n0 & 255) + seg * 32;
        int h = nnl >> 6, dk = nnl & 63;
        size_t roff = (region == 1) ? 11796480ull : 0ull;
        bf16* op = outb + roff + (((size_t)(b_ * 4 + h) * 360 + s) << 6) + dk;
        #pragma unroll
        for (int j = 0; j < 4; j++)
          *(uint4*)(op + j * 8) = *(uint4*)(&Cs[lr][seg * 32 + j * 8]);
      } else {
        int nn = tid >> 1;
        int nnl = (n0 & 255) + nn;
        int h = nnl >> 6, dk = nnl & 63;
        int msub = (tid & 1) * 32;
        #pragma unroll
        for (int j0 = 0; j0 < 32; j0 += 8){
          int m = mbase + msub + j0;                 // 8-aligned: never crosses batch
          int b_ = m / 360, s = m - b_ * 360;
          bf16 tmp[8];
          #pragma unroll
          for (int t = 0; t < 8; t++) tmp[t] = Cs[msub + j0 + t][nn];
          *(uint4*)(outb + 23592960ull + ((size_t)((b_ * 4 + h) * 64 + dk)) * 360 + s) =
              *(uint4*)tmp;
        }
      }
    }
    __syncthreads();
  }
}

// attn4: one block per (b_local,h), 512 thr / 8 waves, 3 q-tiles/wave,
// single-pass softmax (scores O(1); pad queries s=0 -> uniform). K LDS-resident.
__global__ __launch_bounds__(512) void attn4(
    const bf16* __restrict__ q, const bf16* __restrict__ kk, const bf16* __restrict__ vt,
    const int* __restrict__ src, bf16* __restrict__ ctx)
{
  __shared__ bf16 Ks[360][72];
  __shared__ bf16 Pb[8][16][48];
  int bh = blockIdx.x;
  int b = bh >> 2, h = bh & 3;
  int wave = threadIdx.x >> 6, lane = threadIdx.x & 63;
  int r = lane & 15, qd = lane >> 4;
  const bf16* qb = q  + (size_t)bh * 360 * 64;
  const bf16* kb = kk + (size_t)bh * 360 * 64;
  const bf16* vb = vt + (size_t)bh * 64 * 360;
  const int* srow = src + b * 360;

  for (int c = threadIdx.x; c < 2880; c += 512){
    int row = c >> 3, g = c & 7;
    *(uint4*)(&Ks[row][g * 8]) = *(const uint4*)(kb + row * 64 + g * 8);
  }
  __syncthreads();

  frag8 qa0[3], qa1[3];
  bool qp[3];
  float lsum[3];
  f32x4 accO[3][4];
  #pragma unroll
  for (int tl = 0; tl < 3; tl++){
    int qt = wave * 3 + tl;
    int qg = qt * 16 + r;
    int qrow = qg > 359 ? 359 : qg;
    qa0[tl] = *(const frag8*)(qb + qrow * 64 + qd * 8);
    qa1[tl] = *(const frag8*)(qb + qrow * 64 + 32 + qd * 8);
    qp[tl] = (qg < 360) && (srow[qg] == 799);
    lsum[tl] = 0.f;
    #pragma unroll
    for (int dt = 0; dt < 4; dt++) accO[tl][dt] = (f32x4){0.f, 0.f, 0.f, 0.f};
  }

  for (int kc = 0; kc < 12; kc++){
    int krow0 = kc * 32 + r;      if (krow0 > 359) krow0 = 359;
    int krow1 = kc * 32 + 16 + r; if (krow1 > 359) krow1 = 359;
    frag8 kf00 = *(const frag8*)(&Ks[krow0][qd * 8]);
    frag8 kf01 = *(const frag8*)(&Ks[krow0][32 + qd * 8]);
    frag8 kf10 = *(const frag8*)(&Ks[krow1][qd * 8]);
    frag8 kf11 = *(const frag8*)(&Ks[krow1][32 + qd * 8]);
    frag8 vf[4];
    #pragma unroll
    for (int dt = 0; dt < 4; dt++)
      vf[dt] = *(const frag8*)(vb + (size_t)(dt * 16 + r) * 360 + kc * 32 + qd * 8);

    #pragma unroll
    for (int tl = 0; tl < 3; tl++){
      f32x4 z0 = {0.f, 0.f, 0.f, 0.f}, z1 = {0.f, 0.f, 0.f, 0.f};
      z0 = __builtin_amdgcn_mfma_f32_16x16x32_bf16(kf00, qa0[tl], z0, 0, 0, 0);
      z0 = __builtin_amdgcn_mfma_f32_16x16x32_bf16(kf01, qa1[tl], z0, 0, 0, 0);
      z1 = __builtin_amdgcn_mfma_f32_16x16x32_bf16(kf10, qa0[tl], z1, 0, 0, 0);
      z1 = __builtin_amdgcn_mfma_f32_16x16x32_bf16(kf11, qa1[tl], z1, 0, 0, 0);
      float p0[4], p1[4];
      #pragma unroll
      for (int i = 0; i < 4; i++){
        int key0 = kc * 32 + qd * 4 + i;
        int key1 = key0 + 16;
        float s0 = z0[i] * 0.125f, s1 = z1[i] * 0.125f;
        if (qp[tl]){ s0 = 0.0f; s1 = 0.0f; }
        p0[i] = (key0 < 360) ? __expf(s0) : 0.0f;
        p1[i] = (key1 < 360) ? __expf(s1) : 0.0f;
        lsum[tl] += p0[i] + p1[i];
      }
      *(uint2*)(&Pb[wave][r][qd * 4])      = make_uint2(pack2(p0[0], p0[1]), pack2(p0[2], p0[3]));
      *(uint2*)(&Pb[wave][r][16 + qd * 4]) = make_uint2(pack2(p1[0], p1[1]), pack2(p1[2], p1[3]));
      asm volatile("s_waitcnt lgkmcnt(0)" ::: "memory");
      frag8 pa = *(const frag8*)(&Pb[wave][r][qd * 8]);
      #pragma unroll
      for (int dt = 0; dt < 4; dt++)
        accO[tl][dt] = __builtin_amdgcn_mfma_f32_16x16x32_bf16(pa, vf[dt], accO[tl][dt], 0, 0, 0);
      asm volatile("s_waitcnt lgkmcnt(0)" ::: "memory");
    }
  }

  #pragma unroll
  for (int tl = 0; tl < 3; tl++){
    int qt = wave * 3 + tl;
    float ls = lsum[tl];
    ls += __shfl_xor(ls, 16, 64);
    ls += __shfl_xor(ls, 32, 64);
    float invl = 1.0f / ls;
    #pragma unroll
    for (int i = 0; i < 4; i++){
      float inv_i = __shfl(invl, qd * 4 + i, 64);
      int qglob = qt * 16 + qd * 4 + i;
      if (qglob < 360){
        #pragma unroll
        for (int dt = 0; dt < 4; dt++)
          ctx[((size_t)(b * 360 + qglob)) * 256 + h * 64 + dt * 16 + r] =
              __float2bfloat16(accO[tl][dt][i] * inv_i);
      }
    }
  }
}

// head: one wave per (b, pair), vectorized loads. 5824 blocks x 4 waves.
__global__ __launch_bounds__(256) void head_k(
    const bf16* __restrict__ x, const int* __restrict__ src,
    const float* __restrict__ wl, const float* __restrict__ bl,
    float* __restrict__ out)
{
  int widx = blockIdx.x * 4 + (threadIdx.x >> 6);
  if (widx >= 23296) return;
  int lane = threadIdx.x & 63;
  int b = widx / 91, p = widx - b * 91;

  int i = 0, rem = p;
  while (rem >= 13 - i){ rem -= 13 - i; i++; }
  int j = i + 1 + rem;
  int base = 12 * i - (i * (i - 1)) / 2;
  int pe = base + (j - i) - 1;
  int eb = 28 + 2 * pe;

  int g = lane >> 3, sub = lane & 7;
  int idxg;
  if (g == 0) idxg = 2 * i;
  else if (g == 1) idxg = 2 * i + 1;
  else if (g == 2) idxg = 2 * j;
  else if (g == 3) idxg = 2 * j + 1;
  else idxg = eb + (g - 4);
  bool zm = !(g >= 4 && j == 13);

  float a0 = 0.f, a1 = 0.f, a2 = 0.f;
  if (zm){
    const uint4*  xr4 = (const uint4*)(x + ((size_t)b * 360 + idxg) * 256 + sub * 32);
    const float4* wr4 = (const float4*)(wl + (size_t)(g * 256 + sub * 32) * 3);
    uint4 xv[4];
    #pragma unroll
    for (int c = 0; c < 4; c++) xv[c] = xr4[c];
    float4 wv[24];
    #pragma unroll
    for (int c = 0; c < 24; c++) wv[c] = wr4[c];
    const bf16*  xa = (const bf16*)xv;
    const float* wa = (const float*)wv;
    #pragma unroll
    for (int t = 0; t < 32; t++){
      float f = __bfloat162float(xa[t]);
      a0 += f * wa[t * 3 + 0];
      a1 += f * wa[t * 3 + 1];
      a2 += f * wa[t * 3 + 2];
    }
  }
  #pragma unroll
  for (int o = 1; o < 64; o <<= 1){
    a0 += __shfl_xor(a0, o, 64);
    a1 += __shfl_xor(a1, o, 64);
    a2 += __shfl_xor(a2, o, 64);
  }
  if (lane == 0){
    const int* sr = src + b * 360;
    int ti = sr[2 * i], ai = sr[2 * i + 1], tj = sr[2 * j], aj = sr[2 * j + 1];
    bool c1 = (ai == 2) || (aj == 2);
    bool c2 = (tj == 1) || (ai == 1) || (aj == 1);
    bool c3 = (ti == 799) || (tj == 799) || (ai == 0) || (aj == 0);
    bool c4 = false;
    if (j < 13){
      int es = 28 + 4 * pe;
      c4 = (sr[es] == 1) || (sr[es + 1] == 1) || (sr[es + 2] == 1) || (sr[es + 3] == 1);
    }
    bool m1 = c3 || c4, m2 = m1 || c2, m3 = m2 || c1;
    float* op = out + ((size_t)b * 91 + p) * 3;
    op[0] = m1 ? -1.0e9f : (a0 + bl[0]);
    op[1] = m2 ? -1.0e9f : (a1 + bl[1]);
    op[2] = m3 ? -1.0e9f : (a2 + bl[2]);
  }
}

extern "C" void kernel_launch(void* const* d_in, const int* in_sizes, int n_in,
                              void* d_out, int out_size, void* d_ws, size_t ws_size,
                              hipStream_t stream)
{
  const int*   src = (const int*)  d_in[0];
  const float* emb = (const float*)d_in[1];
  const float* wq  = (const float*)d_in[2];  const float* bq = (const float*)d_in[3];
  const float* wk  = (const float*)d_in[4];  const float* bk = (const float*)d_in[5];
  const float* wv  = (const float*)d_in[6];  const float* bv = (const float*)d_in[7];
  const float* wo  = (const float*)d_in[8];  const float* bo = (const float*)d_in[9];
  const float* n1a = (const float*)d_in[10]; const float* n1b = (const float*)d_in[11];
  const float* n2a = (const float*)d_in[12]; const float* n2b = (const float*)d_in[13];
  const float* w1  = (const float*)d_in[14]; const float* b1 = (const float*)d_in[15];
  const float* w2  = (const float*)d_in[16]; const float* b2 = (const float*)d_in[17];
  const float* wl  = (const float*)d_in[18]; const float* bl = (const float*)d_in[19];
  float* out = (float*)d_out;

  if (ws_size < 191365120ull) return;

  char* ws = (char*)d_ws;
  bf16* x   = (bf16*)(ws);                    // [92160][256]
  bf16* xn  = (bf16*)(ws + 47185920ull);      // [92160][256]
  char* R   = ws + 94371840ull;
  bf16* qh   = (bf16*)(R);                    // [512][360][64]; k +11796480 el; v^T +23592960 el
  bf16* kh   = (bf16*)(R + 23592960ull);
  bf16* vth  = (bf16*)(R + 47185920ull);      // [512][64][360]
  bf16* ctxh = (bf16*)(R + 70778880ull);      // [46080][256]
  bf16* hbuf = (bf16*)(R);                    // ffn phase: [23040][2048] per M-chunk
  bf16* wT   = (bf16*)(ws + 188743680ull);
  bf16* wqT = wT;
  bf16* wkT = wT + 65536;
  bf16* wvT = wT + 131072;
  bf16* woT = wT + 196608;
  bf16* w1T = wT + 262144;       // [2048][256]
  bf16* w2T = w1T + 524288;      // [256][2048]

  cvt_transpose<<<dim3(8, 8),   256, 0, stream>>>(wqT, wq, 256, 256);
  cvt_transpose<<<dim3(8, 8),   256, 0, stream>>>(wkT, wk, 256, 256);
  cvt_transpose<<<dim3(8, 8),   256, 0, stream>>>(wvT, wv, 256, 256);
  cvt_transpose<<<dim3(8, 8),   256, 0, stream>>>(woT, wo, 256, 256);
  cvt_transpose<<<dim3(8, 64),  256, 0, stream>>>(w1T, w1, 256, 2048);
  cvt_transpose<<<dim3(64, 8),  256, 0, stream>>>(w2T, w2, 2048, 256);

  embed_ln1<<<23040, 256, 0, stream>>>(src, emb, n1a, n1b, x, xn);

  dim3 gqkv(360, 6), gh(360, 2);
  for (int half = 0; half < 2; half++){
    size_t ro = (size_t)half * 46080;
    const bf16* xnh = xn + ro * 256;
    gemm_bt<4><<<gqkv, 256, 0, stream>>>(xnh, 256, wqT, 256, nullptr, qh, nullptr,
                                         768, 256, bq, bk, bv);
    attn4<<<512, 512, 0, stream>>>(qh, kh, vth, src + ro, ctxh);
    gemm_bt<3><<<gh, 256, 0, stream>>>(ctxh, 256, woT, 256, bo, nullptr, x + ro * 256,
                                       256, 256, nullptr, nullptr, nullptr);
  }

  ln_k<<<23040, 256, 0, stream>>>(x, n2a, n2b, xn);

  for (int mc = 0; mc < 4; mc++){
    const bf16* xnc = xn + (size_t)mc * 23040 * 256;
    bf16* xc = x + (size_t)mc * 23040 * 256;
    gemm_bt<2><<<dim3(180, 16), 256, 0, stream>>>(xnc, 256, w1T, 256, b1, hbuf, nullptr,
                                                  2048, 256, nullptr, nullptr, nullptr);
    gemm_bt<3><<<dim3(180, 2), 256, 0, stream>>>(hbuf, 2048, w2T, 2048, b2, nullptr, xc,
                                                 256, 2048, nullptr, nullptr, nullptr);
  }

  head_k<<<5824, 256, 0, stream>>>(x, src, wl, bl, out);
}

// Round 7
// 939.052 us; speedup vs baseline: 1.0481x; 1.0481x over previous
//
#include <hip/hip_runtime.h>
#include <hip/hip_bf16.h>
#include <math.h>

// ---------------------------------------------------------------------------
// Round 6: (1) head_k: block-per-batch, x rows 0..191 LDS-staged once, wl
// register-resident across the pair loop (R6 head_k was 78us: VGPR=32 ->
// serialized load/waitcnt chains, wl reloaded per wave). (2) gemm_bt: Cs
// aliased over As/Bs (33.4KB -> 17.4KB LDS/block) for occupancy.
// ws layout unchanged (191,365,120 B).
// ---------------------------------------------------------------------------

using bf16 = __hip_bfloat16;
typedef __attribute__((ext_vector_type(8))) short frag8;
typedef __attribute__((ext_vector_type(4))) float f32x4;

static __device__ __forceinline__ float wave_sum64(float v){
  #pragma unroll
  for (int o = 32; o >= 1; o >>= 1) v += __shfl_xor(v, o, 64);
  return v;
}

static __device__ __forceinline__ void gl_lds16(const bf16* g, bf16* l){
  __builtin_amdgcn_global_load_lds((const __attribute__((address_space(1))) void*)g,
                                   (__attribute__((address_space(3))) void*)l, 16, 0, 0);
}

static __device__ __forceinline__ unsigned pack2(float a, float b){
  union { bf16 h[2]; unsigned u; } u;
  u.h[0] = __float2bfloat16(a); u.h[1] = __float2bfloat16(b);
  return u.u;
}

// tiled fp32->bf16 transpose: dst[n*K+k] = src[k*N+n]. grid (K/32, N/32), 256 thr.
__global__ __launch_bounds__(256) void cvt_transpose(bf16* __restrict__ dst,
                                                     const float* __restrict__ src,
                                                     int K, int N){
  __shared__ float t[32][33];
  int kb = blockIdx.x * 32, nb = blockIdx.y * 32;
  int tx = threadIdx.x & 31, ty = threadIdx.x >> 5;
  #pragma unroll
  for (int dy = 0; dy < 32; dy += 8)
    t[ty + dy][tx] = src[(size_t)(kb + ty + dy) * N + nb + tx];
  __syncthreads();
  #pragma unroll
  for (int dy = 0; dy < 32; dy += 8)
    dst[(size_t)(nb + ty + dy) * K + kb + tx] = __float2bfloat16(t[tx][ty + dy]);
}

// embed + PE + scale -> x (bf16), LN1 -> xn (bf16). one wave/row, grid 23040.
__global__ __launch_bounds__(256) void embed_ln1(
    const int* __restrict__ src, const float* __restrict__ emb,
    const float* __restrict__ na, const float* __restrict__ nb,
    bf16* __restrict__ x, bf16* __restrict__ xn)
{
  int row  = blockIdx.x * 4 + (threadIdx.x >> 6);
  int lane = threadIdx.x & 63;
  int s = row % 360;
  int tok = src[row];
  float4 v = *(const float4*)(emb + (size_t)tok * 256 + lane * 4);
  float vv[4] = {v.x, v.y, v.z, v.w};
  if (s < 340){
    const float C = (-2.0f / 256.0f) * 13.287712379549449f;
    #pragma unroll
    for (int t = 0; t < 4; t++){
      int c = lane * 4 + t;
      float ang = (float)s * exp2f(C * (float)c);
      float pe = (c & 1) ? cosf(ang) : sinf(ang);
      vv[t] = 16.0f * vv[t] + pe;
    }
  }
  float sum = wave_sum64(vv[0] + vv[1] + vv[2] + vv[3]);
  float mu = sum * (1.0f / 256.0f);
  float d0 = vv[0]-mu, d1 = vv[1]-mu, d2 = vv[2]-mu, d3 = vv[3]-mu;
  float sq = wave_sum64(d0*d0 + d1*d1 + d2*d2 + d3*d3);
  float inv = 1.0f / (sqrtf(sq * (1.0f / 255.0f)) + 1e-6f);
  bf16 xo[4] = { __float2bfloat16(vv[0]), __float2bfloat16(vv[1]),
                 __float2bfloat16(vv[2]), __float2bfloat16(vv[3]) };
  *(uint2*)(x + (size_t)row * 256 + lane * 4) = *(uint2*)xo;
  float4 a4 = *(const float4*)(na + lane * 4);
  float4 b4 = *(const float4*)(nb + lane * 4);
  bf16 o4[4] = { __float2bfloat16(a4.x * d0 * inv + b4.x),
                 __float2bfloat16(a4.y * d1 * inv + b4.y),
                 __float2bfloat16(a4.z * d2 * inv + b4.z),
                 __float2bfloat16(a4.w * d3 * inv + b4.w) };
  *(uint2*)(xn + (size_t)row * 256 + lane * 4) = *(uint2*)o4;
}

// LN over bf16 x -> bf16 xn. one wave per row. grid 23040.
__global__ __launch_bounds__(256) void ln_k(
    const bf16* __restrict__ x, const float* __restrict__ na,
    const float* __restrict__ nb, bf16* __restrict__ xn)
{
  int row  = blockIdx.x * 4 + (threadIdx.x >> 6);
  int lane = threadIdx.x & 63;
  uint2 raw = *(const uint2*)(x + (size_t)row * 256 + lane * 4);
  bf16* xr = (bf16*)&raw;
  float v0 = __bfloat162float(xr[0]), v1 = __bfloat162float(xr[1]);
  float v2 = __bfloat162float(xr[2]), v3 = __bfloat162float(xr[3]);
  float sum = wave_sum64(v0 + v1 + v2 + v3);
  float mu = sum * (1.0f / 256.0f);
  float d0 = v0-mu, d1 = v1-mu, d2 = v2-mu, d3 = v3-mu;
  float sq = wave_sum64(d0*d0 + d1*d1 + d2*d2 + d3*d3);
  float inv = 1.0f / (sqrtf(sq * (1.0f / 255.0f)) + 1e-6f);
  float4 a4 = *(const float4*)(na + lane * 4);
  float4 b4 = *(const float4*)(nb + lane * 4);
  bf16 o4[4] = { __float2bfloat16(a4.x * d0 * inv + b4.x),
                 __float2bfloat16(a4.y * d1 * inv + b4.y),
                 __float2bfloat16(a4.z * d2 * inv + b4.z),
                 __float2bfloat16(a4.w * d3 * inv + b4.w) };
  *(uint2*)(xn + (size_t)row * 256 + lane * 4) = *(uint2*)o4;
}

// C = A[M][K] @ Bt[N][K]^T + bias. 128x128 tile, BK=32, global_load_lds staging,
// LDS-staged coalesced epilogue (Cs aliases As/Bs: total LDS 17.4KB).
// MODE 2: relu, bf16 row-major [M][N]
// MODE 3: bf16 residual in-place: xres[m*256+n] += acc (+bias)
// MODE 4: merged QKV (N=768): region = n0>>8: 0 q-layout, 1 k-layout, 2 v^T
template<int MODE>
__global__ __launch_bounds__(256) void gemm_bt(
    const bf16* __restrict__ A, int lda,
    const bf16* __restrict__ Bt, int ldb,
    const float* __restrict__ bias,
    bf16* __restrict__ outb, bf16* __restrict__ xres,
    int N, int K,
    const float* __restrict__ bq, const float* __restrict__ bk,
    const float* __restrict__ bv)
{
  __shared__ __align__(16) char smem[17408];   // max(As+Bs = 16384, Cs = 17408)
  bf16* As = (bf16*)smem;
  bf16* Bs = (bf16*)(smem + 8192);
  bf16 (*Cs)[136] = (bf16 (*)[136])smem;
  int m0 = blockIdx.x * 128, n0 = blockIdx.y * 128;
  int tid = threadIdx.x;
  int wave = tid >> 6, lane = tid & 63;
  int wm = (wave >> 1) * 64, wn = (wave & 1) * 64;
  int r = lane & 15, qd = lane >> 4;

  int slot0 = wave * 128 + lane;
  int row0 = slot0 >> 2, c0 = slot0 & 3;
  int row1 = (slot0 + 64) >> 2, c1 = (slot0 + 64) & 3;
  const bf16* ag0 = A  + (size_t)(m0 + row0) * lda + c0 * 8;
  const bf16* ag1 = A  + (size_t)(m0 + row1) * lda + c1 * 8;
  const bf16* bg0 = Bt + (size_t)(n0 + row0) * ldb + c0 * 8;
  const bf16* bg1 = Bt + (size_t)(n0 + row1) * ldb + c1 * 8;
  bf16* lA0 = As + (size_t)(wave * 128) * 8;
  bf16* lA1 = As + (size_t)(wave * 128 + 64) * 8;
  bf16* lB0 = Bs + (size_t)(wave * 128) * 8;
  bf16* lB1 = Bs + (size_t)(wave * 128 + 64) * 8;

  f32x4 acc[4][4];
  #pragma unroll
  for (int mt = 0; mt < 4; mt++)
    #pragma unroll
    for (int nt = 0; nt < 4; nt++) acc[mt][nt] = (f32x4){0.f, 0.f, 0.f, 0.f};

  for (int k0 = 0; k0 < K; k0 += 32){
    gl_lds16(ag0, lA0); gl_lds16(ag1, lA1);
    gl_lds16(bg0, lB0); gl_lds16(bg1, lB1);
    ag0 += 32; ag1 += 32; bg0 += 32; bg1 += 32;
    __syncthreads();
    frag8 af[4], bfr[4];
    #pragma unroll
    for (int t = 0; t < 4; t++){
      af[t]  = *(const frag8*)(As + (wm + t * 16 + r) * 32 + qd * 8);
      bfr[t] = *(const frag8*)(Bs + (wn + t * 16 + r) * 32 + qd * 8);
    }
    #pragma unroll
    for (int mt = 0; mt < 4; mt++)
      #pragma unroll
      for (int nt = 0; nt < 4; nt++)
        acc[mt][nt] = __builtin_amdgcn_mfma_f32_16x16x32_bf16(af[mt], bfr[nt], acc[mt][nt], 0, 0, 0);
    __syncthreads();
  }

  const int region = (MODE == 4) ? (n0 >> 8) : 0;
  const float* bb = (MODE == 4) ? (region == 0 ? bq : region == 1 ? bk : bv) : bias;

  #pragma unroll
  for (int half = 0; half < 2; half++){
    if ((wave >> 1) == half){
      #pragma unroll
      for (int mt = 0; mt < 4; mt++)
        #pragma unroll
        for (int nt = 0; nt < 4; nt++)
          #pragma unroll
          for (int i = 0; i < 4; i++){
            int lm = mt * 16 + qd * 4 + i;
            int ln = wn + nt * 16 + r;
            float v = acc[mt][nt][i];
            if (MODE == 2){ v += bb[n0 + ln]; v = fmaxf(v, 0.0f); }
            else if (MODE == 3){ if (bb) v += bb[n0 + ln]; }
            else { v += bb[(n0 & 255) + ln]; }
            Cs[lm][ln] = __float2bfloat16(v);
          }
    }
    __syncthreads();
    int mbase = m0 + half * 64;
    if (MODE == 2){
      int lr = tid >> 2, seg = tid & 3;
      bf16* op = outb + (size_t)(mbase + lr) * N + n0 + seg * 32;
      #pragma unroll
      for (int j = 0; j < 4; j++)
        *(uint4*)(op + j * 8) = *(uint4*)(&Cs[lr][seg * 32 + j * 8]);
    } else if (MODE == 3){
      int lr = tid >> 2, seg = tid & 3;
      bf16* op = xres + (size_t)(mbase + lr) * 256 + n0 + seg * 32;
      #pragma unroll
      for (int j = 0; j < 4; j++){
        uint4 cv = *(uint4*)(&Cs[lr][seg * 32 + j * 8]);
        uint4 xv = *(uint4*)(op + j * 8);
        bf16* ca = (bf16*)&cv; bf16* xa = (bf16*)&xv;
        bf16 o8[8];
        #pragma unroll
        for (int t = 0; t < 8; t++)
          o8[t] = __float2bfloat16(__bfloat162float(ca[t]) + __bfloat162float(xa[t]));
        *(uint4*)(op + j * 8) = *(uint4*)o8;
      }
    } else {
      if (region < 2){
        int lr = tid >> 2, seg = tid & 3;
        int m = mbase + lr;
        int b_ = m / 360, s = m - b_ * 360;
        int nnl = (n0 & 255) + seg * 32;
        int h = nnl >> 6, dk = nnl & 63;
        size_t roff = (region == 1) ? 11796480ull : 0ull;
        bf16* op = outb + roff + (((size_t)(b_ * 4 + h) * 360 + s) << 6) + dk;
        #pragma unroll
        for (int j = 0; j < 4; j++)
          *(uint4*)(op + j * 8) = *(uint4*)(&Cs[lr][seg * 32 + j * 8]);
      } else {
        int nn = tid >> 1;
        int nnl = (n0 & 255) + nn;
        int h = nnl >> 6, dk = nnl & 63;
        int msub = (tid & 1) * 32;
        #pragma unroll
        for (int j0 = 0; j0 < 32; j0 += 8){
          int m = mbase + msub + j0;
          int b_ = m / 360, s = m - b_ * 360;
          bf16 tmp[8];
          #pragma unroll
          for (int t = 0; t < 8; t++) tmp[t] = Cs[msub + j0 + t][nn];
          *(uint4*)(outb + 23592960ull + ((size_t)((b_ * 4 + h) * 64 + dk)) * 360 + s) =
              *(uint4*)tmp;
        }
      }
    }
    __syncthreads();
  }
}

// attn4: one block per (b_local,h), 512 thr / 8 waves, 3 q-tiles/wave,
// single-pass softmax (scores O(1); pad queries s=0 -> uniform). K LDS-resident.
__global__ __launch_bounds__(512) void attn4(
    const bf16* __restrict__ q, const bf16* __restrict__ kk, const bf16* __restrict__ vt,
    const int* __restrict__ src, bf16* __restrict__ ctx)
{
  __shared__ bf16 Ks[360][72];
  __shared__ bf16 Pb[8][16][48];
  int bh = blockIdx.x;
  int b = bh >> 2, h = bh & 3;
  int wave = threadIdx.x >> 6, lane = threadIdx.x & 63;
  int r = lane & 15, qd = lane >> 4;
  const bf16* qb = q  + (size_t)bh * 360 * 64;
  const bf16* kb = kk + (size_t)bh * 360 * 64;
  const bf16* vb = vt + (size_t)bh * 64 * 360;
  const int* srow = src + b * 360;

  for (int c = threadIdx.x; c < 2880; c += 512){
    int row = c >> 3, g = c & 7;
    *(uint4*)(&Ks[row][g * 8]) = *(const uint4*)(kb + row * 64 + g * 8);
  }
  __syncthreads();

  frag8 qa0[3], qa1[3];
  bool qp[3];
  float lsum[3];
  f32x4 accO[3][4];
  #pragma unroll
  for (int tl = 0; tl < 3; tl++){
    int qt = wave * 3 + tl;
    int qg = qt * 16 + r;
    int qrow = qg > 359 ? 359 : qg;
    qa0[tl] = *(const frag8*)(qb + qrow * 64 + qd * 8);
    qa1[tl] = *(const frag8*)(qb + qrow * 64 + 32 + qd * 8);
    qp[tl] = (qg < 360) && (srow[qg] == 799);
    lsum[tl] = 0.f;
    #pragma unroll
    for (int dt = 0; dt < 4; dt++) accO[tl][dt] = (f32x4){0.f, 0.f, 0.f, 0.f};
  }

  for (int kc = 0; kc < 12; kc++){
    int krow0 = kc * 32 + r;      if (krow0 > 359) krow0 = 359;
    int krow1 = kc * 32 + 16 + r; if (krow1 > 359) krow1 = 359;
    frag8 kf00 = *(const frag8*)(&Ks[krow0][qd * 8]);
    frag8 kf01 = *(const frag8*)(&Ks[krow0][32 + qd * 8]);
    frag8 kf10 = *(const frag8*)(&Ks[krow1][qd * 8]);
    frag8 kf11 = *(const frag8*)(&Ks[krow1][32 + qd * 8]);
    frag8 vf[4];
    #pragma unroll
    for (int dt = 0; dt < 4; dt++)
      vf[dt] = *(const frag8*)(vb + (size_t)(dt * 16 + r) * 360 + kc * 32 + qd * 8);

    #pragma unroll
    for (int tl = 0; tl < 3; tl++){
      f32x4 z0 = {0.f, 0.f, 0.f, 0.f}, z1 = {0.f, 0.f, 0.f, 0.f};
      z0 = __builtin_amdgcn_mfma_f32_16x16x32_bf16(kf00, qa0[tl], z0, 0, 0, 0);
      z0 = __builtin_amdgcn_mfma_f32_16x16x32_bf16(kf01, qa1[tl], z0, 0, 0, 0);
      z1 = __builtin_amdgcn_mfma_f32_16x16x32_bf16(kf10, qa0[tl], z1, 0, 0, 0);
      z1 = __builtin_amdgcn_mfma_f32_16x16x32_bf16(kf11, qa1[tl], z1, 0, 0, 0);
      float p0[4], p1[4];
      #pragma unroll
      for (int i = 0; i < 4; i++){
        int key0 = kc * 32 + qd * 4 + i;
        int key1 = key0 + 16;
        float s0 = z0[i] * 0.125f, s1 = z1[i] * 0.125f;
        if (qp[tl]){ s0 = 0.0f; s1 = 0.0f; }
        p0[i] = (key0 < 360) ? __expf(s0) : 0.0f;
        p1[i] = (key1 < 360) ? __expf(s1) : 0.0f;
        lsum[tl] += p0[i] + p1[i];
      }
      *(uint2*)(&Pb[wave][r][qd * 4])      = make_uint2(pack2(p0[0], p0[1]), pack2(p0[2], p0[3]));
      *(uint2*)(&Pb[wave][r][16 + qd * 4]) = make_uint2(pack2(p1[0], p1[1]), pack2(p1[2], p1[3]));
      asm volatile("s_waitcnt lgkmcnt(0)" ::: "memory");
      frag8 pa = *(const frag8*)(&Pb[wave][r][qd * 8]);
      #pragma unroll
      for (int dt = 0; dt < 4; dt++)
        accO[tl][dt] = __builtin_amdgcn_mfma_f32_16x16x32_bf16(pa, vf[dt], accO[tl][dt], 0, 0, 0);
      asm volatile("s_waitcnt lgkmcnt(0)" ::: "memory");
    }
  }

  #pragma unroll
  for (int tl = 0; tl < 3; tl++){
    int qt = wave * 3 + tl;
    float ls = lsum[tl];
    ls += __shfl_xor(ls, 16, 64);
    ls += __shfl_xor(ls, 32, 64);
    float invl = 1.0f / ls;
    #pragma unroll
    for (int i = 0; i < 4; i++){
      float inv_i = __shfl(invl, qd * 4 + i, 64);
      int qglob = qt * 16 + qd * 4 + i;
      if (qglob < 360){
        #pragma unroll
        for (int dt = 0; dt < 4; dt++)
          ctx[((size_t)(b * 360 + qglob)) * 256 + h * 64 + dt * 16 + r] =
              __float2bfloat16(accO[tl][dt][i] * inv_i);
      }
    }
  }
}

// head: one block per batch (grid 256, 4 waves). x rows 0..191 staged in LDS,
// wl register-resident per lane, waves sweep pairs p = wave, wave+4, ...
__global__ __launch_bounds__(256) void head_k(
    const bf16* __restrict__ x, const int* __restrict__ src,
    const float* __restrict__ wl, const float* __restrict__ bl,
    float* __restrict__ out)
{
  __shared__ bf16 Xs[192][264];    // stride 264: spreads the 8 g-rows across banks
  int b = blockIdx.x;
  int tid = threadIdx.x;
  int wave = tid >> 6, lane = tid & 63;
  int g = lane >> 3, sub = lane & 7;

  const bf16* xb = x + (size_t)b * 360 * 256;
  for (int it = 0; it < 24; it++){
    int idx = tid + it * 256;        // 6144 uint4 total
    int row = idx >> 5, col = idx & 31;
    *(uint4*)(&Xs[row][col * 8]) = *(const uint4*)(xb + row * 256 + col * 8);
  }

  // wl fragment for this lane: rows g*256+sub*32 .. +31, 3 cols each
  float wv[96];
  {
    const float4* wr4 = (const float4*)(wl + (size_t)(g * 256 + sub * 32) * 3);
    #pragma unroll
    for (int c = 0; c < 24; c++) *(float4*)(&wv[c * 4]) = wr4[c];
  }
  float bl0 = bl[0], bl1 = bl[1], bl2 = bl[2];
  const int* sr = src + b * 360;
  __syncthreads();

  for (int p = wave; p < 91; p += 4){
    int i = 0, rem = p;
    while (rem >= 13 - i){ rem -= 13 - i; i++; }
    int j = i + 1 + rem;
    int base = 12 * i - (i * (i - 1)) / 2;
    int pe = base + (j - i) - 1;
    int eb = 28 + 2 * pe;

    int idxg;
    if (g == 0) idxg = 2 * i;
    else if (g == 1) idxg = 2 * i + 1;
    else if (g == 2) idxg = 2 * j;
    else if (g == 3) idxg = 2 * j + 1;
    else idxg = eb + (g - 4);
    bool zm = !(g >= 4 && j == 13);

    uint4 xv[4];
    #pragma unroll
    for (int c = 0; c < 4; c++) xv[c] = *(uint4*)(&Xs[idxg][sub * 32 + c * 8]);
    const bf16* xa = (const bf16*)xv;
    float a0 = 0.f, a1 = 0.f, a2 = 0.f;
    #pragma unroll
    for (int t = 0; t < 32; t++){
      float f = zm ? __bfloat162float(xa[t]) : 0.0f;
      a0 += f * wv[t * 3 + 0];
      a1 += f * wv[t * 3 + 1];
      a2 += f * wv[t * 3 + 2];
    }
    #pragma unroll
    for (int o = 1; o < 64; o <<= 1){
      a0 += __shfl_xor(a0, o, 64);
      a1 += __shfl_xor(a1, o, 64);
      a2 += __shfl_xor(a2, o, 64);
    }
    if (lane == 0){
      int ti = sr[2 * i], ai = sr[2 * i + 1], tj = sr[2 * j], aj = sr[2 * j + 1];
      bool c1 = (ai == 2) || (aj == 2);
      bool c2 = (tj == 1) || (ai == 1) || (aj == 1);
      bool c3 = (ti == 799) || (tj == 799) || (ai == 0) || (aj == 0);
      bool c4 = false;
      if (j < 13){
        int es = 28 + 4 * pe;
        c4 = (sr[es] == 1) || (sr[es + 1] == 1) || (sr[es + 2] == 1) || (sr[es + 3] == 1);
      }
      bool m1 = c3 || c4, m2 = m1 || c2, m3 = m2 || c1;
      float* op = out + ((size_t)b * 91 + p) * 3;
      op[0] = m1 ? -1.0e9f : (a0 + bl0);
      op[1] = m2 ? -1.0e9f : (a1 + bl1);
      op[2] = m3 ? -1.0e9f : (a2 + bl2);
    }
  }
}

extern "C" void kernel_launch(void* const* d_in, const int* in_sizes, int n_in,
                              void* d_out, int out_size, void* d_ws, size_t ws_size,
                              hipStream_t stream)
{
  const int*   src = (const int*)  d_in[0];
  const float* emb = (const float*)d_in[1];
  const float* wq  = (const float*)d_in[2];  const float* bq = (const float*)d_in[3];
  const float* wk  = (const float*)d_in[4];  const float* bk = (const float*)d_in[5];
  const float* wv  = (const float*)d_in[6];  const float* bv = (const float*)d_in[7];
  const float* wo  = (const float*)d_in[8];  const float* bo = (const float*)d_in[9];
  const float* n1a = (const float*)d_in[10]; const float* n1b = (const float*)d_in[11];
  const float* n2a = (const float*)d_in[12]; const float* n2b = (const float*)d_in[13];
  const float* w1  = (const float*)d_in[14]; const float* b1 = (const float*)d_in[15];
  const float* w2  = (const float*)d_in[16]; const float* b2 = (const float*)d_in[17];
  const float* wl  = (const float*)d_in[18]; const float* bl = (const float*)d_in[19];
  float* out = (float*)d_out;

  if (ws_size < 191365120ull) return;

  char* ws = (char*)d_ws;
  bf16* x   = (bf16*)(ws);
  bf16* xn  = (bf16*)(ws + 47185920ull);
  char* R   = ws + 94371840ull;
  bf16* qh   = (bf16*)(R);
  bf16* kh   = (bf16*)(R + 23592960ull);
  bf16* vth  = (bf16*)(R + 47185920ull);
  bf16* ctxh = (bf16*)(R + 70778880ull);
  bf16* hbuf = (bf16*)(R);
  bf16* wT   = (bf16*)(ws + 188743680ull);
  bf16* wqT = wT;
  bf16* wkT = wT + 65536;
  bf16* wvT = wT + 131072;
  bf16* woT = wT + 196608;
  bf16* w1T = wT + 262144;
  bf16* w2T = w1T + 524288;

  cvt_transpose<<<dim3(8, 8),   256, 0, stream>>>(wqT, wq, 256, 256);
  cvt_transpose<<<dim3(8, 8),   256, 0, stream>>>(wkT, wk, 256, 256);
  cvt_transpose<<<dim3(8, 8),   256, 0, stream>>>(wvT, wv, 256, 256);
  cvt_transpose<<<dim3(8, 8),   256, 0, stream>>>(woT, wo, 256, 256);
  cvt_transpose<<<dim3(8, 64),  256, 0, stream>>>(w1T, w1, 256, 2048);
  cvt_transpose<<<dim3(64, 8),  256, 0, stream>>>(w2T, w2, 2048, 256);

  embed_ln1<<<23040, 256, 0, stream>>>(src, emb, n1a, n1b, x, xn);

  dim3 gqkv(360, 6), gh(360, 2);
  for (int half = 0; half < 2; half++){
    size_t ro = (size_t)half * 46080;
    const bf16* xnh = xn + ro * 256;
    gemm_bt<4><<<gqkv, 256, 0, stream>>>(xnh, 256, wqT, 256, nullptr, qh, nullptr,
                                         768, 256, bq, bk, bv);
    attn4<<<512, 512, 0, stream>>>(qh, kh, vth, src + ro, ctxh);
    gemm_bt<3><<<gh, 256, 0, stream>>>(ctxh, 256, woT, 256, bo, nullptr, x + ro * 256,
                                       256, 256, nullptr, nullptr, nullptr);
  }

  ln_k<<<23040, 256, 0, stream>>>(x, n2a, n2b, xn);

  for (int mc = 0; mc < 4; mc++){
    const bf16* xnc = xn + (size_t)mc * 23040 * 256;
    bf16* xc = x + (size_t)mc * 23040 * 256;
    gemm_bt<2><<<dim3(180, 16), 256, 0, stream>>>(xnc, 256, w1T, 256, b1, hbuf, nullptr,
                                                  2048, 256, nullptr, nullptr, nullptr);
    gemm_bt<3><<<dim3(180, 2), 256, 0, stream>>>(hbuf, 2048, w2T, 2048, b2, nullptr, xc,
                                                 256, 2048, nullptr, nullptr, nullptr);
  }

  head_k<<<256, 256, 0, stream>>>(x, src, wl, bl, out);
}